// Round 1
// baseline (633.098 us; speedup 1.0000x reference)
//
#include <hip/hip_runtime.h>
#include <hip/hip_bf16.h>
#include <math.h>

// DeepSpeed MoE block on MI355X.
// Pipeline: ln_gate -> scan(1 wave) -> scatter -> convT(W1) -> gemm1(gelu) ->
//           convT(W2) -> gemm2(+b2) -> combine.
// Expert GEMMs: bf16-input fp32-accum MFMA 16x16x32, m97-style 128x128 tile,
// global_load_lds(16B) staging, B pre-transposed during fp32->bf16 conversion.

#define T_TOK 4096
#define HD 1024
#define NE 8
#define FD 4096
#define CAPN 1024

typedef __attribute__((ext_vector_type(8))) short short8;
typedef __attribute__((ext_vector_type(4))) float f32x4;

__device__ __forceinline__ unsigned short f2b(float f) {
  __hip_bfloat16 h = __float2bfloat16(f);
  unsigned short u;
  __builtin_memcpy(&u, &h, 2);
  return u;
}

// ---------------- LayerNorm + gating (softmax + top-2) ----------------
__global__ __launch_bounds__(256) void k_ln_gate(
    const float* __restrict__ x, const float* __restrict__ gamma,
    const float* __restrict__ beta, const float* __restrict__ wg,
    unsigned short* __restrict__ xn, float* __restrict__ gates,
    float2* __restrict__ vals, int2* __restrict__ eidx) {
  const int t = blockIdx.x;
  const int tid = threadIdx.x;
  const int lane = tid & 63, wid = tid >> 6;
  __shared__ float red[4];
  __shared__ float pr[4][8];

  const float4 v = ((const float4*)(x + (size_t)t * HD))[tid];
  float s = v.x + v.y + v.z + v.w;
#pragma unroll
  for (int o = 32; o > 0; o >>= 1) s += __shfl_down(s, o);
  if (lane == 0) red[wid] = s;
  __syncthreads();
  const float mean = (red[0] + red[1] + red[2] + red[3]) * (1.0f / HD);
  float dv[4];
  dv[0] = v.x - mean; dv[1] = v.y - mean; dv[2] = v.z - mean; dv[3] = v.w - mean;
  float q = dv[0]*dv[0] + dv[1]*dv[1] + dv[2]*dv[2] + dv[3]*dv[3];
  __syncthreads();
#pragma unroll
  for (int o = 32; o > 0; o >>= 1) q += __shfl_down(q, o);
  if (lane == 0) red[wid] = q;
  __syncthreads();
  const float var = (red[0] + red[1] + red[2] + red[3]) * (1.0f / HD);
  const float rs = 1.0f / sqrtf(var + 1e-5f);

  const float4 gm = ((const float4*)gamma)[tid];
  const float4 bt = ((const float4*)beta)[tid];
  float xv[4];
  xv[0] = dv[0] * rs * gm.x + bt.x;
  xv[1] = dv[1] * rs * gm.y + bt.y;
  xv[2] = dv[2] * rs * gm.z + bt.z;
  xv[3] = dv[3] * rs * gm.w + bt.w;
  ushort4 o4;
  o4.x = f2b(xv[0]); o4.y = f2b(xv[1]); o4.z = f2b(xv[2]); o4.w = f2b(xv[3]);
  ((ushort4*)(xn + (size_t)t * HD))[tid] = o4;

  // logits partials: p[e] += xn_c * wg[c][e]
  float p[8];
#pragma unroll
  for (int e = 0; e < 8; e++) p[e] = 0.f;
  const int c0 = tid * 4;
#pragma unroll
  for (int i = 0; i < 4; i++) {
    const float4 w0 = ((const float4*)(wg + (size_t)(c0 + i) * NE))[0];
    const float4 w1 = ((const float4*)(wg + (size_t)(c0 + i) * NE))[1];
    p[0] += xv[i] * w0.x; p[1] += xv[i] * w0.y;
    p[2] += xv[i] * w0.z; p[3] += xv[i] * w0.w;
    p[4] += xv[i] * w1.x; p[5] += xv[i] * w1.y;
    p[6] += xv[i] * w1.z; p[7] += xv[i] * w1.w;
  }
#pragma unroll
  for (int e = 0; e < 8; e++)
#pragma unroll
    for (int o = 32; o > 0; o >>= 1) p[e] += __shfl_down(p[e], o);
  if (lane == 0) {
#pragma unroll
    for (int e = 0; e < 8; e++) pr[wid][e] = p[e];
  }
  __syncthreads();
  if (tid == 0) {
    float lg[8];
#pragma unroll
    for (int e = 0; e < 8; e++) lg[e] = pr[0][e] + pr[1][e] + pr[2][e] + pr[3][e];
    float mx = lg[0];
#pragma unroll
    for (int e = 1; e < 8; e++) mx = fmaxf(mx, lg[e]);
    float ex[8], sum = 0.f;
#pragma unroll
    for (int e = 0; e < 8; e++) { ex[e] = expf(lg[e] - mx); sum += ex[e]; }
    const float inv = 1.0f / sum;
    float g[8];
#pragma unroll
    for (int e = 0; e < 8; e++) { g[e] = ex[e] * inv; gates[(size_t)t * 8 + e] = g[e]; }
    int i0 = 0;
    for (int e = 1; e < 8; e++) if (g[e] > g[i0]) i0 = e;           // strict > = first max (jax tie order)
    int i1 = (i0 == 0) ? 1 : 0;
    for (int e = 0; e < 8; e++) if (e != i0 && g[e] > g[i1]) i1 = e;
    vals[t] = make_float2(g[i0], g[i1]);
    eidx[t] = make_int2(i0, i1);
  }
}

// ---------------- capacity scan (single wave, ballot prefix) ----------------
__global__ __launch_bounds__(64) void k_scan(
    const int2* __restrict__ eidx, const float2* __restrict__ vals,
    const float* __restrict__ gates, int* __restrict__ ppad,
    float2* __restrict__ w, float* __restrict__ out_tail) {
  __shared__ int s0[T_TOK], s1[T_TOK];
  const int lane = threadIdx.x;
  for (int i = lane; i < T_TOK; i += 64) {
    int2 e2 = eidx[i];
    s0[i] = e2.x; s1[i] = e2.y;
  }
  __syncthreads();
  const unsigned long long lt = (lane == 63) ? 0x7fffffffffffffffull
                                             : ((1ull << lane) - 1ull);
  int cnt[8], ce[8];
#pragma unroll
  for (int e = 0; e < 8; e++) cnt[e] = 0;
  for (int j = 0; j < 2; j++) {
    const int* sj = j ? s1 : s0;
    for (int base = 0; base < T_TOK; base += 64) {
      const int my = sj[base + lane];
      int pos = 0;
#pragma unroll
      for (int e = 0; e < 8; e++) {
        unsigned long long m = __ballot(my == e);
        if (my == e) pos = cnt[e] + __popcll(m & lt);
        cnt[e] += __popcll(m);
      }
      ppad[(base + lane) * 2 + j] = (pos < CAPN) ? pos : CAPN;
    }
    if (j == 0) {
#pragma unroll
      for (int e = 0; e < 8; e++) ce[e] = cnt[e];
    }
  }
  // gate weight normalization
  for (int base = 0; base < T_TOK; base += 64) {
    const int t = base + lane;
    const float2 v = vals[t];
    const int p0 = ppad[2 * t], p1 = ppad[2 * t + 1];
    const float k0 = (p0 < CAPN) ? v.x : 0.f;
    const float k1 = (p1 < CAPN) ? v.y : 0.f;
    const float inv = 1.0f / (k0 + k1 + 1e-9f);
    w[t] = make_float2(k0 * inv, k1 * inv);
  }
  // me reduction + l_aux + counts
  float acc[8];
#pragma unroll
  for (int e = 0; e < 8; e++) acc[e] = 0.f;
  for (int t = lane; t < T_TOK; t += 64) {
    const float4 a = ((const float4*)(gates + (size_t)t * 8))[0];
    const float4 b = ((const float4*)(gates + (size_t)t * 8))[1];
    acc[0] += a.x; acc[1] += a.y; acc[2] += a.z; acc[3] += a.w;
    acc[4] += b.x; acc[5] += b.y; acc[6] += b.z; acc[7] += b.w;
  }
#pragma unroll
  for (int e = 0; e < 8; e++)
#pragma unroll
    for (int o = 32; o > 0; o >>= 1) acc[e] += __shfl_down(acc[e], o);
  if (lane == 0) {
    float la = 0.f;
#pragma unroll
    for (int e = 0; e < 8; e++)
      la += (acc[e] * (1.0f / T_TOK)) * ((float)ce[e] * (1.0f / T_TOK));
    out_tail[0] = la * 8.0f;  // mean(me*ce)*E*E = E*sum
#pragma unroll
    for (int e = 0; e < 8; e++) out_tail[1 + e] = (float)cnt[e];
  }
}

// ---------------- scatter kept tokens into expert buffer ----------------
__global__ __launch_bounds__(128) void k_scatter(
    const unsigned short* __restrict__ xn, const int2* __restrict__ eidx,
    const int* __restrict__ ppad, unsigned short* __restrict__ buf) {
  const int b = blockIdx.x;
  const int t = b >> 1, j = b & 1;
  const int pp = ppad[2 * t + j];
  if (pp >= CAPN) return;
  const int2 e2 = eidx[t];
  const int e = j ? e2.y : e2.x;
  const uint4* s = (const uint4*)(xn + (size_t)t * HD);
  uint4* d = (uint4*)(buf + ((size_t)e * CAPN + pp) * HD);
  d[threadIdx.x] = s[threadIdx.x];
}

// ---------------- fp32->bf16 convert + transpose (per expert slab) ----------------
// in: [E][R][C] f32 ; out: [E][C][R] bf16.  grid (C/64, R/64, E), 256 thr.
__global__ __launch_bounds__(256) void k_convT(
    const float* __restrict__ Win, unsigned short* __restrict__ Wout,
    int R, int C) {
  __shared__ __align__(16) unsigned short tile[64][72];
  const int e = blockIdx.z;
  const int c0 = blockIdx.x * 64, r0 = blockIdx.y * 64;
  const int tid = threadIdx.x;
  const int r = tid >> 2, qq = tid & 3;
  const float* src = Win + ((size_t)e * R + r0 + r) * C + c0;
#pragma unroll
  for (int i = 0; i < 4; i++) {
    const int cc = qq * 16 + i * 4;
    const float4 v = *(const float4*)(src + cc);
    tile[cc + 0][r] = f2b(v.x);
    tile[cc + 1][r] = f2b(v.y);
    tile[cc + 2][r] = f2b(v.z);
    tile[cc + 3][r] = f2b(v.w);
  }
  __syncthreads();
  const int cr = tid >> 2;
  unsigned short* dst = Wout + ((size_t)e * C + c0 + cr) * R + r0 + qq * 16;
  *(uint4*)(dst + 0) = *(const uint4*)&tile[cr][qq * 16];
  *(uint4*)(dst + 8) = *(const uint4*)&tile[cr][qq * 16 + 8];
}

// ---------------- grouped GEMM, 128x128 tile, mfma 16x16x32 bf16 ----------------
// MODE 0: h1 = gelu(buf @ W1T^T + b1) -> bf16 [8192][FD]
// MODE 1: y  = h1 @ W2T^T + b2        -> f32  [8192][HD]
template <int MODE>
__global__ __launch_bounds__(256) void k_gemm(
    const unsigned short* __restrict__ A, const unsigned short* __restrict__ Bt,
    const float* __restrict__ bias, void* __restrict__ out) {
  constexpr int K = MODE ? FD : HD;
  constexpr int N = MODE ? HD : FD;
  const int nt = blockIdx.x, mt = blockIdx.y;
  const int e = mt >> 3;
  const size_t m0 = (size_t)mt * 128;
  const int n0 = nt * 128;
  __shared__ __align__(16) unsigned short lA[128 * 32];
  __shared__ __align__(16) unsigned short lB[128 * 32];
  const int tid = threadIdx.x;
  const int lane = tid & 63, wid = tid >> 6;
  const int sr = tid >> 2, sq = tid & 3;
  const unsigned short* gA = A + m0 * (size_t)K + (size_t)sq * 8;
  const unsigned short* gB = Bt + ((size_t)e * N + n0) * K + (size_t)sq * 8;
  const int wr = wid >> 1, wc = wid & 1;
  const int l15 = lane & 15, half = lane >> 4;

  f32x4 acc[4][4];
  const f32x4 fz = {0.f, 0.f, 0.f, 0.f};
#pragma unroll
  for (int mi = 0; mi < 4; mi++)
#pragma unroll
    for (int ni = 0; ni < 4; ni++) acc[mi][ni] = fz;

  for (int k0 = 0; k0 < K; k0 += 32) {
    __syncthreads();
    __builtin_amdgcn_global_load_lds(
        (const __attribute__((address_space(1))) void*)(gA + (size_t)sr * K + k0),
        (__attribute__((address_space(3))) void*)(lA + wid * 512), 16, 0, 0);
    __builtin_amdgcn_global_load_lds(
        (const __attribute__((address_space(1))) void*)(gA + (size_t)(sr + 64) * K + k0),
        (__attribute__((address_space(3))) void*)(lA + 2048 + wid * 512), 16, 0, 0);
    __builtin_amdgcn_global_load_lds(
        (const __attribute__((address_space(1))) void*)(gB + (size_t)sr * K + k0),
        (__attribute__((address_space(3))) void*)(lB + wid * 512), 16, 0, 0);
    __builtin_amdgcn_global_load_lds(
        (const __attribute__((address_space(1))) void*)(gB + (size_t)(sr + 64) * K + k0),
        (__attribute__((address_space(3))) void*)(lB + 2048 + wid * 512), 16, 0, 0);
    __syncthreads();
    short8 af[4], bfr[4];
#pragma unroll
    for (int i = 0; i < 4; i++) {
      af[i]  = *(const short8*)&lA[(wr * 64 + i * 16 + l15) * 32 + half * 8];
      bfr[i] = *(const short8*)&lB[(wc * 64 + i * 16 + l15) * 32 + half * 8];
    }
#pragma unroll
    for (int mi = 0; mi < 4; mi++)
#pragma unroll
      for (int ni = 0; ni < 4; ni++)
        acc[mi][ni] = __builtin_amdgcn_mfma_f32_16x16x32_bf16(af[mi], bfr[ni],
                                                              acc[mi][ni], 0, 0, 0);
  }

  const float* brow = bias + (size_t)e * N;
  if (MODE == 0) {
    unsigned short* h1 = (unsigned short*)out;
#pragma unroll
    for (int mi = 0; mi < 4; mi++)
#pragma unroll
      for (int ni = 0; ni < 4; ni++) {
        const int col = n0 + wc * 64 + ni * 16 + l15;
        const float bv = brow[col];
#pragma unroll
        for (int r = 0; r < 4; r++) {
          const size_t row = m0 + wr * 64 + mi * 16 + half * 4 + r;
          const float pre = acc[mi][ni][r] + bv;
          const float g = 0.5f * pre * (1.0f + erff(pre * 0.70710678118654752f));
          h1[row * (size_t)N + col] = f2b(g);
        }
      }
  } else {
    float* y = (float*)out;
#pragma unroll
    for (int mi = 0; mi < 4; mi++)
#pragma unroll
      for (int ni = 0; ni < 4; ni++) {
        const int col = n0 + wc * 64 + ni * 16 + l15;
        const float bv = brow[col];
#pragma unroll
        for (int r = 0; r < 4; r++) {
          const size_t row = m0 + wr * 64 + mi * 16 + half * 4 + r;
          y[row * (size_t)N + col] = acc[mi][ni][r] + bv;
        }
      }
  }
}

// ---------------- combine: out = x + sum_j w_j * y[slot_j] ----------------
__global__ __launch_bounds__(256) void k_combine(
    const float* __restrict__ x, const float* __restrict__ y,
    const int2* __restrict__ eidx, const int* __restrict__ ppad,
    const float2* __restrict__ w, float* __restrict__ out) {
  const int t = blockIdx.x, tid = threadIdx.x;
  const float2 wt = w[t];
  const int2 e2 = eidx[t];
  const int p0 = ppad[2 * t], p1 = ppad[2 * t + 1];
  float4 o = ((const float4*)(x + (size_t)t * HD))[tid];
  if (p0 < CAPN) {
    const float4 a = ((const float4*)(y + ((size_t)e2.x * CAPN + p0) * HD))[tid];
    o.x += wt.x * a.x; o.y += wt.x * a.y; o.z += wt.x * a.z; o.w += wt.x * a.w;
  }
  if (p1 < CAPN) {
    const float4 a = ((const float4*)(y + ((size_t)e2.y * CAPN + p1) * HD))[tid];
    o.x += wt.y * a.x; o.y += wt.y * a.y; o.z += wt.y * a.z; o.w += wt.y * a.w;
  }
  ((float4*)(out + (size_t)t * HD))[tid] = o;
}

extern "C" void kernel_launch(void* const* d_in, const int* in_sizes, int n_in,
                              void* d_out, int out_size, void* d_ws, size_t ws_size,
                              hipStream_t stream) {
  const float* x     = (const float*)d_in[0];
  const float* gamma = (const float*)d_in[1];
  const float* beta  = (const float*)d_in[2];
  const float* wg    = (const float*)d_in[3];
  const float* W1    = (const float*)d_in[4];
  const float* b1    = (const float*)d_in[5];
  const float* W2    = (const float*)d_in[6];
  const float* b2    = (const float*)d_in[7];
  float* out = (float*)d_out;

  char* ws = (char*)d_ws;
  // ws layout (needs ~184.3 MiB)
  unsigned short* xn  = (unsigned short*)(ws);                  //  8 MiB
  unsigned short* buf = (unsigned short*)(ws + (8ull << 20));   // 16 MiB
  unsigned short* h1  = (unsigned short*)(ws + (24ull << 20));  // 64 MiB
  float* y            = (float*)(ws + (88ull << 20));           // 32 MiB
  unsigned short* WT  = (unsigned short*)(ws + (120ull << 20)); // 64 MiB (W1T, later W2T)
  float* gates        = (float*)(ws + (184ull << 20));          // 128 KiB
  float2* vals        = (float2*)(ws + (184ull << 20) + (128ull << 10));
  int2* eidx          = (int2*)(ws + (184ull << 20) + (160ull << 10));
  int* ppad           = (int*)(ws + (184ull << 20) + (192ull << 10));
  float2* wnrm        = (float2*)(ws + (184ull << 20) + (224ull << 10));

  hipMemsetAsync(buf, 0, (16ull << 20), stream);  // zero expert buffer
  k_ln_gate<<<T_TOK, 256, 0, stream>>>(x, gamma, beta, wg, xn, gates, vals, eidx);
  k_scan<<<1, 64, 0, stream>>>(eidx, vals, gates, ppad, wnrm,
                               out + (size_t)T_TOK * HD);
  k_scatter<<<T_TOK * 2, 128, 0, stream>>>(xn, eidx, ppad, buf);
  k_convT<<<dim3(FD / 64, HD / 64, NE), 256, 0, stream>>>(W1, WT, HD, FD);
  k_gemm<0><<<dim3(FD / 128, 64), 256, 0, stream>>>(buf, WT, b1, h1);
  k_convT<<<dim3(HD / 64, FD / 64, NE), 256, 0, stream>>>(W2, WT, FD, HD);
  k_gemm<1><<<dim3(HD / 128, 64), 256, 0, stream>>>(h1, WT, b2, y);
  k_combine<<<T_TOK, 256, 0, stream>>>(x, y, eidx, ppad, wnrm, out);
}

// Round 2
// 556.418 us; speedup vs baseline: 1.1378x; 1.1378x over previous
//
#include <hip/hip_runtime.h>
#include <hip/hip_bf16.h>
#include <math.h>

// DeepSpeed MoE block on MI355X.
// ln_gate -> scan(wave0 ballot cumsum || waves1-3 gates reduce) -> scatter ->
// convT(W1) -> gemm256<0>(gelu) -> convT(W2) -> gemm256<1>(split-K) -> combine.
// GEMM: 256x256 tile, 8 waves, BK=32, 4-deep LDS ring, counted vmcnt (8/4/0),
// raw s_barrier, setprio, XOR-swizzled LDS (2-way residual = free).

#define T_TOK 4096
#define HD 1024
#define NE 8
#define FD 4096
#define CAPN 1024

typedef __attribute__((ext_vector_type(8))) short short8;
typedef __attribute__((ext_vector_type(4))) float f32x4;

__device__ __forceinline__ unsigned short f2b(float f) {
  __hip_bfloat16 h = __float2bfloat16(f);
  unsigned short u;
  __builtin_memcpy(&u, &h, 2);
  return u;
}

// ---------------- LayerNorm + gating (softmax + top-2) ----------------
__global__ __launch_bounds__(256) void k_ln_gate(
    const float* __restrict__ x, const float* __restrict__ gamma,
    const float* __restrict__ beta, const float* __restrict__ wg,
    unsigned short* __restrict__ xn, float* __restrict__ gates,
    float2* __restrict__ vals, int2* __restrict__ eidx) {
  const int t = blockIdx.x;
  const int tid = threadIdx.x;
  const int lane = tid & 63, wid = tid >> 6;
  __shared__ float red[4];
  __shared__ float pr[4][8];

  const float4 v = ((const float4*)(x + (size_t)t * HD))[tid];
  float s = v.x + v.y + v.z + v.w;
#pragma unroll
  for (int o = 32; o > 0; o >>= 1) s += __shfl_down(s, o);
  if (lane == 0) red[wid] = s;
  __syncthreads();
  const float mean = (red[0] + red[1] + red[2] + red[3]) * (1.0f / HD);
  float dv[4];
  dv[0] = v.x - mean; dv[1] = v.y - mean; dv[2] = v.z - mean; dv[3] = v.w - mean;
  float q = dv[0]*dv[0] + dv[1]*dv[1] + dv[2]*dv[2] + dv[3]*dv[3];
  __syncthreads();
#pragma unroll
  for (int o = 32; o > 0; o >>= 1) q += __shfl_down(q, o);
  if (lane == 0) red[wid] = q;
  __syncthreads();
  const float var = (red[0] + red[1] + red[2] + red[3]) * (1.0f / HD);
  const float rs = 1.0f / sqrtf(var + 1e-5f);

  const float4 gm = ((const float4*)gamma)[tid];
  const float4 bt = ((const float4*)beta)[tid];
  float xv[4];
  xv[0] = dv[0] * rs * gm.x + bt.x;
  xv[1] = dv[1] * rs * gm.y + bt.y;
  xv[2] = dv[2] * rs * gm.z + bt.z;
  xv[3] = dv[3] * rs * gm.w + bt.w;
  ushort4 o4;
  o4.x = f2b(xv[0]); o4.y = f2b(xv[1]); o4.z = f2b(xv[2]); o4.w = f2b(xv[3]);
  ((ushort4*)(xn + (size_t)t * HD))[tid] = o4;

  float p[8];
#pragma unroll
  for (int e = 0; e < 8; e++) p[e] = 0.f;
  const int c0 = tid * 4;
#pragma unroll
  for (int i = 0; i < 4; i++) {
    const float4 w0 = ((const float4*)(wg + (size_t)(c0 + i) * NE))[0];
    const float4 w1 = ((const float4*)(wg + (size_t)(c0 + i) * NE))[1];
    p[0] += xv[i] * w0.x; p[1] += xv[i] * w0.y;
    p[2] += xv[i] * w0.z; p[3] += xv[i] * w0.w;
    p[4] += xv[i] * w1.x; p[5] += xv[i] * w1.y;
    p[6] += xv[i] * w1.z; p[7] += xv[i] * w1.w;
  }
#pragma unroll
  for (int e = 0; e < 8; e++)
#pragma unroll
    for (int o = 32; o > 0; o >>= 1) p[e] += __shfl_down(p[e], o);
  if (lane == 0) {
#pragma unroll
    for (int e = 0; e < 8; e++) pr[wid][e] = p[e];
  }
  __syncthreads();
  if (tid == 0) {
    float lg[8];
#pragma unroll
    for (int e = 0; e < 8; e++) lg[e] = pr[0][e] + pr[1][e] + pr[2][e] + pr[3][e];
    float mx = lg[0];
#pragma unroll
    for (int e = 1; e < 8; e++) mx = fmaxf(mx, lg[e]);
    float ex[8], sum = 0.f;
#pragma unroll
    for (int e = 0; e < 8; e++) { ex[e] = expf(lg[e] - mx); sum += ex[e]; }
    const float inv = 1.0f / sum;
    float g[8];
#pragma unroll
    for (int e = 0; e < 8; e++) { g[e] = ex[e] * inv; gates[(size_t)t * 8 + e] = g[e]; }
    int i0 = 0;
    for (int e = 1; e < 8; e++) if (g[e] > g[i0]) i0 = e;
    int i1 = (i0 == 0) ? 1 : 0;
    for (int e = 0; e < 8; e++) if (e != i0 && g[e] > g[i1]) i1 = e;
    vals[t] = make_float2(g[i0], g[i1]);
    eidx[t] = make_int2(i0, i1);
  }
}

// ---------------- scan: wave0 ballot cumsum; waves1-3 gates reduce ----------------
__global__ __launch_bounds__(256) void k_scan(
    const int2* __restrict__ eidx, const float* __restrict__ gates,
    int* __restrict__ ppad, float* __restrict__ out_tail) {
  __shared__ int s0[T_TOK], s1[T_TOK];
  __shared__ float mw[3][8];
  __shared__ int ce_sh[8], cnt_sh[8];
  const int tid = threadIdx.x;
  const int lane = tid & 63, wid = tid >> 6;
  for (int i = tid; i < T_TOK; i += 256) {
    int2 e2 = eidx[i];
    s0[i] = e2.x; s1[i] = e2.y;
  }
  __syncthreads();
  if (wid == 0) {
    const unsigned long long lt = (lane == 63) ? 0x7fffffffffffffffull
                                               : ((1ull << lane) - 1ull);
    int cnt[8];
#pragma unroll
    for (int e = 0; e < 8; e++) cnt[e] = 0;
    for (int j = 0; j < 2; j++) {
      const int* sj = j ? s1 : s0;
      for (int base = 0; base < T_TOK; base += 64) {
        const int my = sj[base + lane];
        int pos = 0;
#pragma unroll
        for (int e = 0; e < 8; e++) {
          unsigned long long m = __ballot(my == e);
          if (my == e) pos = cnt[e] + __popcll(m & lt);
          cnt[e] += __popcll(m);
        }
        ppad[(base + lane) * 2 + j] = (pos < CAPN) ? pos : CAPN;
      }
      if (j == 0 && lane == 0) {
#pragma unroll
        for (int e = 0; e < 8; e++) ce_sh[e] = cnt[e];
      }
    }
    if (lane == 0) {
#pragma unroll
      for (int e = 0; e < 8; e++) cnt_sh[e] = cnt[e];
    }
  } else {
    float acc[8];
#pragma unroll
    for (int e = 0; e < 8; e++) acc[e] = 0.f;
    for (int t = tid - 64; t < T_TOK; t += 192) {
      const float4 a = ((const float4*)(gates + (size_t)t * 8))[0];
      const float4 b = ((const float4*)(gates + (size_t)t * 8))[1];
      acc[0] += a.x; acc[1] += a.y; acc[2] += a.z; acc[3] += a.w;
      acc[4] += b.x; acc[5] += b.y; acc[6] += b.z; acc[7] += b.w;
    }
#pragma unroll
    for (int e = 0; e < 8; e++)
#pragma unroll
      for (int o = 32; o > 0; o >>= 1) acc[e] += __shfl_down(acc[e], o);
    if (lane == 0) {
#pragma unroll
      for (int e = 0; e < 8; e++) mw[wid - 1][e] = acc[e];
    }
  }
  __syncthreads();
  if (tid == 0) {
    float la = 0.f;
#pragma unroll
    for (int e = 0; e < 8; e++) {
      const float me = (mw[0][e] + mw[1][e] + mw[2][e]) * (1.0f / T_TOK);
      la += me * ((float)ce_sh[e] * (1.0f / T_TOK));
    }
    out_tail[0] = la * 8.0f;
#pragma unroll
    for (int e = 0; e < 8; e++) out_tail[1 + e] = (float)cnt_sh[e];
  }
}

// ---------------- scatter kept tokens into expert buffer ----------------
__global__ __launch_bounds__(128) void k_scatter(
    const unsigned short* __restrict__ xn, const int2* __restrict__ eidx,
    const int* __restrict__ ppad, unsigned short* __restrict__ buf) {
  const int b = blockIdx.x;
  const int t = b >> 1, j = b & 1;
  const int pp = ppad[2 * t + j];
  if (pp >= CAPN) return;
  const int2 e2 = eidx[t];
  const int e = j ? e2.y : e2.x;
  const uint4* s = (const uint4*)(xn + (size_t)t * HD);
  uint4* d = (uint4*)(buf + ((size_t)e * CAPN + pp) * HD);
  d[threadIdx.x] = s[threadIdx.x];
}

// ---------------- fp32->bf16 convert + transpose ----------------
__global__ __launch_bounds__(256) void k_convT(
    const float* __restrict__ Win, unsigned short* __restrict__ Wout,
    int R, int C) {
  __shared__ __align__(16) unsigned short tile[64][72];
  const int e = blockIdx.z;
  const int c0 = blockIdx.x * 64, r0 = blockIdx.y * 64;
  const int tid = threadIdx.x;
  const int r = tid >> 2, qq = tid & 3;
  const float* src = Win + ((size_t)e * R + r0 + r) * C + c0;
#pragma unroll
  for (int i = 0; i < 4; i++) {
    const int cc = qq * 16 + i * 4;
    const float4 v = *(const float4*)(src + cc);
    tile[cc + 0][r] = f2b(v.x);
    tile[cc + 1][r] = f2b(v.y);
    tile[cc + 2][r] = f2b(v.z);
    tile[cc + 3][r] = f2b(v.w);
  }
  __syncthreads();
  const int cr = tid >> 2;
  unsigned short* dst = Wout + ((size_t)e * C + c0 + cr) * R + r0 + qq * 16;
  *(uint4*)(dst + 0) = *(const uint4*)&tile[cr][qq * 16];
  *(uint4*)(dst + 8) = *(const uint4*)&tile[cr][qq * 16 + 8];
}

// ---------------- 256x256 GEMM, 8 waves, BK=32, 4-ring LDS, counted vmcnt ----
// MODE 0: h1 = gelu(buf @ W1T^T + b1) -> bf16 ; SPLITK=1
// MODE 1: y  = h1 @ W2T^T (no bias)   -> f32 partial per z ; SPLITK 1 or 2
#define GLL16(SRC, DSTOFF) __builtin_amdgcn_global_load_lds( \
    (const __attribute__((address_space(1))) void*)(SRC), \
    (__attribute__((address_space(3))) void*)(smem + (DSTOFF)), 16, 0, 0)

#define STAGE_A(T) { const size_t ko = (size_t)(T) * 32; const int rbo = ((T)&3)*32768; \
  GLL16(gA + ko + oA0, rbo + ldsAd); \
  GLL16(gA + ko + oA1, rbo + 8192 + ldsAd); }

#define STAGE_B(T) { const size_t ko = (size_t)(T) * 32; const int rbo = ((T)&3)*32768; \
  GLL16(gB + ko + oA0, rbo + ldsBd); \
  GLL16(gB + ko + oA1, rbo + 8192 + ldsBd); }

#define TILE(T, DOST, VMW) { \
  const unsigned char* rb = smem + ((T)&3)*32768; \
  short8 af[4], bfv[4]; \
  _Pragma("unroll") for (int i = 0; i < 4; ++i) { \
    af[i]  = *(const short8*)(rb + offA + i*1024); \
    bfv[i] = *(const short8*)(rb + offB + i*1024); } \
  if (DOST) { STAGE_A((T)+3); } \
  asm volatile("s_barrier" ::: "memory"); \
  __builtin_amdgcn_s_setprio(1); \
  _Pragma("unroll") for (int mi = 0; mi < 4; ++mi) \
    _Pragma("unroll") for (int ni = 0; ni < 4; ++ni) \
      acc[mi][ni] = __builtin_amdgcn_mfma_f32_16x16x32_bf16(af[mi], bfv[ni], acc[mi][ni], 0, 0, 0); \
  __builtin_amdgcn_s_setprio(0); \
  _Pragma("unroll") for (int i = 0; i < 4; ++i) \
    af[i] = *(const short8*)(rb + offA + 4096 + i*1024); \
  if (DOST) { STAGE_B((T)+3); } \
  asm volatile("s_waitcnt lgkmcnt(0)" ::: "memory"); \
  asm volatile("s_waitcnt vmcnt(" #VMW ")" ::: "memory"); \
  asm volatile("s_barrier" ::: "memory"); \
  __builtin_amdgcn_s_setprio(1); \
  _Pragma("unroll") for (int mi = 0; mi < 4; ++mi) \
    _Pragma("unroll") for (int ni = 0; ni < 4; ++ni) \
      acc[4+mi][ni] = __builtin_amdgcn_mfma_f32_16x16x32_bf16(af[mi], bfv[ni], acc[4+mi][ni], 0, 0, 0); \
  __builtin_amdgcn_s_setprio(0); \
}

template <int MODE, int SPLITK>
__global__ __launch_bounds__(512, 2) void k_gemm256(
    const unsigned short* __restrict__ A, const unsigned short* __restrict__ Bt,
    const float* __restrict__ bias, void* __restrict__ out) {
  constexpr int K = MODE ? FD : HD;
  constexpr int N = MODE ? HD : FD;
  constexpr int KLOC = K / SPLITK;
  constexpr int NT = KLOC / 32;
  constexpr int NBT = N / 256;

  __shared__ __align__(16) unsigned char smem[4 * 32768];  // 128 KiB ring

  const int tid = threadIdx.x;
  const int lane = tid & 63, wid = tid >> 6;
  const int l15 = lane & 15, lq = lane >> 4;
  const int wr = wid >> 2, wc = wid & 3;

  // XCD-swizzled block mapping; lin = ((z*NBT + nt)<<5) | mt
  const int nwg = gridDim.x;
  const int per = nwg >> 3;
  const int lin = blockIdx.x;
  const int swz = (lin & 7) * per + (lin >> 3);
  const int mt = swz & 31;
  const int rest = swz >> 5;
  const int nt = rest % NBT;
  const int z = rest / NBT;

  const int e = mt >> 2;
  const size_t m0 = (size_t)mt * 256;
  const int n0 = nt * 256;
  const unsigned short* gA = A + m0 * (size_t)K + (size_t)z * KLOC;
  const unsigned short* gB = Bt + ((size_t)e * N + n0) * (size_t)K + (size_t)z * KLOC;

  // staging source offsets (pre-swizzled): chunk c' = c ^ ((row>>1)&3)
  const int LA0 = tid * 16, LA1 = 8192 + tid * 16;
  const int r0s = LA0 >> 6, c0s = (LA0 >> 4) & 3;
  const int r1s = LA1 >> 6, c1s = (LA1 >> 4) & 3;
  const size_t oA0 = (size_t)r0s * K + (size_t)(c0s ^ ((r0s >> 1) & 3)) * 8;
  const size_t oA1 = (size_t)r1s * K + (size_t)(c1s ^ ((r1s >> 1) & 3)) * 8;
  const int ldsAd = wid * 1024;
  const int ldsBd = 16384 + wid * 1024;

  // fragment ds_read offsets (swizzled to conflict-free: 2 lanes/bank)
  const int rA = wr * 128 + l15;
  const int offA = rA * 64 + ((lq ^ ((rA >> 1) & 3)) << 4);
  const int rB = wc * 64 + l15;
  const int offB = 16384 + rB * 64 + ((lq ^ ((rB >> 1) & 3)) << 4);

  f32x4 acc[8][4];
  const f32x4 fz = {0.f, 0.f, 0.f, 0.f};
#pragma unroll
  for (int mi = 0; mi < 8; mi++)
#pragma unroll
    for (int ni = 0; ni < 4; ni++) acc[mi][ni] = fz;

  // prologue: stage tiles 0,1,2 ; wait tile0 (12 outstanding -> 8)
  STAGE_A(0); STAGE_B(0);
  STAGE_A(1); STAGE_B(1);
  STAGE_A(2); STAGE_B(2);
  asm volatile("s_waitcnt vmcnt(8)" ::: "memory");
  asm volatile("s_barrier" ::: "memory");

  for (int t = 0; t <= NT - 4; ++t) { TILE(t, true, 8); }
  TILE(NT - 3, false, 4);
  TILE(NT - 2, false, 0);
  TILE(NT - 1, false, 63);

  if (MODE == 0) {
    unsigned short* o = (unsigned short*)out;
    const float* brow = bias + (size_t)e * N;
#pragma unroll
    for (int mi = 0; mi < 8; ++mi)
#pragma unroll
      for (int ni = 0; ni < 4; ++ni) {
        const int col = n0 + wc * 64 + ni * 16 + l15;
        const float bv = brow[col];
#pragma unroll
        for (int r = 0; r < 4; ++r) {
          const size_t row = m0 + wr * 128 + mi * 16 + lq * 4 + r;
          const float pre = acc[mi][ni][r] + bv;
          const float g = 0.5f * pre * (1.0f + erff(pre * 0.70710678118654752f));
          o[row * (size_t)N + col] = f2b(g);
        }
      }
  } else {
    float* yp = (float*)out + (size_t)z * (8192ull * 1024ull);
#pragma unroll
    for (int mi = 0; mi < 8; ++mi)
#pragma unroll
      for (int ni = 0; ni < 4; ++ni) {
        const int col = n0 + wc * 64 + ni * 16 + l15;
#pragma unroll
        for (int r = 0; r < 4; ++r) {
          const size_t row = m0 + wr * 128 + mi * 16 + lq * 4 + r;
          yp[row * (size_t)N + col] = acc[mi][ni][r];
        }
      }
  }
}
#undef TILE
#undef STAGE_A
#undef STAGE_B
#undef GLL16

// ---------------- combine: out = x + sum_j w_j * (y[slot_j] + b2[e_j]) ------
template <int SPLIT>
__global__ __launch_bounds__(256) void k_combine(
    const float* __restrict__ x, const float* __restrict__ y0,
    const float* __restrict__ y1, const float* __restrict__ b2,
    const int2* __restrict__ eidx, const int* __restrict__ ppad,
    const float2* __restrict__ vals, float* __restrict__ out) {
  const int t = blockIdx.x, tid = threadIdx.x;
  const float2 v = vals[t];
  const int2 e2 = eidx[t];
  const int p0 = ppad[2 * t], p1 = ppad[2 * t + 1];
  const float k0 = (p0 < CAPN) ? v.x : 0.f;
  const float k1 = (p1 < CAPN) ? v.y : 0.f;
  const float inv = 1.0f / (k0 + k1 + 1e-9f);
  const float w0 = k0 * inv, w1 = k1 * inv;
  float4 o = ((const float4*)(x + (size_t)t * HD))[tid];
  if (p0 < CAPN) {
    const size_t s = ((size_t)e2.x * CAPN + p0) * HD;
    float4 a = ((const float4*)(y0 + s))[tid];
    if (SPLIT == 2) {
      const float4 b = ((const float4*)(y1 + s))[tid];
      a.x += b.x; a.y += b.y; a.z += b.z; a.w += b.w;
    }
    const float4 bb = ((const float4*)(b2 + (size_t)e2.x * HD))[tid];
    o.x += w0 * (a.x + bb.x); o.y += w0 * (a.y + bb.y);
    o.z += w0 * (a.z + bb.z); o.w += w0 * (a.w + bb.w);
  }
  if (p1 < CAPN) {
    const size_t s = ((size_t)e2.y * CAPN + p1) * HD;
    float4 a = ((const float4*)(y0 + s))[tid];
    if (SPLIT == 2) {
      const float4 b = ((const float4*)(y1 + s))[tid];
      a.x += b.x; a.y += b.y; a.z += b.z; a.w += b.w;
    }
    const float4 bb = ((const float4*)(b2 + (size_t)e2.y * HD))[tid];
    o.x += w1 * (a.x + bb.x); o.y += w1 * (a.y + bb.y);
    o.z += w1 * (a.z + bb.z); o.w += w1 * (a.w + bb.w);
  }
  ((float4*)(out + (size_t)t * HD))[tid] = o;
}

extern "C" void kernel_launch(void* const* d_in, const int* in_sizes, int n_in,
                              void* d_out, int out_size, void* d_ws, size_t ws_size,
                              hipStream_t stream) {
  const float* x     = (const float*)d_in[0];
  const float* gamma = (const float*)d_in[1];
  const float* beta  = (const float*)d_in[2];
  const float* wg    = (const float*)d_in[3];
  const float* W1    = (const float*)d_in[4];
  const float* b1    = (const float*)d_in[5];
  const float* W2    = (const float*)d_in[6];
  const float* b2    = (const float*)d_in[7];
  float* out = (float*)d_out;

  char* ws = (char*)d_ws;
  // layout: smalls | xn 8M | buf 16M | h1 64M | WT 64M | y0 32M | y1 32M
  float* gates        = (float*)(ws);                                  // 128K
  float2* vals        = (float2*)(ws + (128ull << 10));                // 32K
  int2* eidx          = (int2*)(ws + (160ull << 10));                  // 32K
  int* ppad           = (int*)(ws + (192ull << 10));                   // 32K
  unsigned short* xn  = (unsigned short*)(ws + (512ull << 10));
  unsigned short* buf = (unsigned short*)(ws + (512ull << 10) + (8ull << 20));
  unsigned short* h1  = (unsigned short*)(ws + (512ull << 10) + (24ull << 20));
  unsigned short* WT  = (unsigned short*)(ws + (512ull << 10) + (88ull << 20));
  float* y0           = (float*)(ws + (512ull << 10) + (152ull << 20));
  float* y1           = (float*)(ws + (512ull << 10) + (184ull << 20));
  const bool splitk = ws_size >= ((217ull << 20));

  k_ln_gate<<<T_TOK, 256, 0, stream>>>(x, gamma, beta, wg, xn, gates, vals, eidx);
  k_scan<<<1, 256, 0, stream>>>(eidx, gates, ppad, out + (size_t)T_TOK * HD);
  k_scatter<<<T_TOK * 2, 128, 0, stream>>>(xn, eidx, ppad, buf);
  k_convT<<<dim3(FD / 64, HD / 64, NE), 256, 0, stream>>>(W1, WT, HD, FD);
  k_gemm256<0, 1><<<512, 512, 0, stream>>>(buf, WT, b1, h1);
  k_convT<<<dim3(HD / 64, FD / 64, NE), 256, 0, stream>>>(W2, WT, FD, HD);
  if (splitk) {
    k_gemm256<1, 2><<<256, 512, 0, stream>>>(h1, WT, nullptr, y0);
    k_combine<2><<<T_TOK, 256, 0, stream>>>(x, y0, y1, b2, eidx, ppad, vals, out);
  } else {
    k_gemm256<1, 1><<<128, 512, 0, stream>>>(h1, WT, nullptr, y0);
    k_combine<1><<<T_TOK, 256, 0, stream>>>(x, y0, y1, b2, eidx, ppad, vals, out);
  }
}

// Round 3
// 530.922 us; speedup vs baseline: 1.1925x; 1.0480x over previous
//
#include <hip/hip_runtime.h>
#include <hip/hip_bf16.h>
#include <math.h>

// DeepSpeed MoE block on MI355X.
// ln_gate -> scan(8-wave parallel ballot cumsum) -> scatter -> convT(W1) ->
// gemm8p<0>(gelu) -> convT(W2) -> gemm8p<1>(split-K) -> combine.
// GEMM: m201-style 256x256 8-phase template: BK=64, 2 K-tiles/iter, 8 waves
// (2M x 4N, per-wave 128x64), 2-deep K-tile double buffer (128 KiB LDS),
// counted vmcnt(8) at phases 4/8 only, XOR-swizzled LDS (conflict-free),
// global_load_lds(16B) staging with pre-swizzled source.

#define T_TOK 4096
#define HD 1024
#define NE 8
#define FD 4096
#define CAPN 1024

typedef __attribute__((ext_vector_type(8))) short short8;
typedef __attribute__((ext_vector_type(4))) float f32x4;

__device__ __forceinline__ unsigned short f2b(float f) {
  __hip_bfloat16 h = __float2bfloat16(f);
  unsigned short u;
  __builtin_memcpy(&u, &h, 2);
  return u;
}

// ---------------- LayerNorm + gating (softmax + top-2) ----------------
__global__ __launch_bounds__(256) void k_ln_gate(
    const float* __restrict__ x, const float* __restrict__ gamma,
    const float* __restrict__ beta, const float* __restrict__ wg,
    unsigned short* __restrict__ xn, float* __restrict__ gates,
    float2* __restrict__ vals, int2* __restrict__ eidx) {
  const int t = blockIdx.x;
  const int tid = threadIdx.x;
  const int lane = tid & 63, wid = tid >> 6;
  __shared__ float red[4];
  __shared__ float pr[4][8];

  const float4 v = ((const float4*)(x + (size_t)t * HD))[tid];
  float s = v.x + v.y + v.z + v.w;
#pragma unroll
  for (int o = 32; o > 0; o >>= 1) s += __shfl_down(s, o);
  if (lane == 0) red[wid] = s;
  __syncthreads();
  const float mean = (red[0] + red[1] + red[2] + red[3]) * (1.0f / HD);
  float dv[4];
  dv[0] = v.x - mean; dv[1] = v.y - mean; dv[2] = v.z - mean; dv[3] = v.w - mean;
  float q = dv[0]*dv[0] + dv[1]*dv[1] + dv[2]*dv[2] + dv[3]*dv[3];
  __syncthreads();
#pragma unroll
  for (int o = 32; o > 0; o >>= 1) q += __shfl_down(q, o);
  if (lane == 0) red[wid] = q;
  __syncthreads();
  const float var = (red[0] + red[1] + red[2] + red[3]) * (1.0f / HD);
  const float rs = 1.0f / sqrtf(var + 1e-5f);

  const float4 gm = ((const float4*)gamma)[tid];
  const float4 bt = ((const float4*)beta)[tid];
  float xv[4];
  xv[0] = dv[0] * rs * gm.x + bt.x;
  xv[1] = dv[1] * rs * gm.y + bt.y;
  xv[2] = dv[2] * rs * gm.z + bt.z;
  xv[3] = dv[3] * rs * gm.w + bt.w;
  ushort4 o4;
  o4.x = f2b(xv[0]); o4.y = f2b(xv[1]); o4.z = f2b(xv[2]); o4.w = f2b(xv[3]);
  ((ushort4*)(xn + (size_t)t * HD))[tid] = o4;

  float p[8];
#pragma unroll
  for (int e = 0; e < 8; e++) p[e] = 0.f;
  const int c0 = tid * 4;
#pragma unroll
  for (int i = 0; i < 4; i++) {
    const float4 w0 = ((const float4*)(wg + (size_t)(c0 + i) * NE))[0];
    const float4 w1 = ((const float4*)(wg + (size_t)(c0 + i) * NE))[1];
    p[0] += xv[i] * w0.x; p[1] += xv[i] * w0.y;
    p[2] += xv[i] * w0.z; p[3] += xv[i] * w0.w;
    p[4] += xv[i] * w1.x; p[5] += xv[i] * w1.y;
    p[6] += xv[i] * w1.z; p[7] += xv[i] * w1.w;
  }
#pragma unroll
  for (int e = 0; e < 8; e++)
#pragma unroll
    for (int o = 32; o > 0; o >>= 1) p[e] += __shfl_down(p[e], o);
  if (lane == 0) {
#pragma unroll
    for (int e = 0; e < 8; e++) pr[wid][e] = p[e];
  }
  __syncthreads();
  if (tid == 0) {
    float lg[8];
#pragma unroll
    for (int e = 0; e < 8; e++) lg[e] = pr[0][e] + pr[1][e] + pr[2][e] + pr[3][e];
    float mx = lg[0];
#pragma unroll
    for (int e = 1; e < 8; e++) mx = fmaxf(mx, lg[e]);
    float ex[8], sum = 0.f;
#pragma unroll
    for (int e = 0; e < 8; e++) { ex[e] = expf(lg[e] - mx); sum += ex[e]; }
    const float inv = 1.0f / sum;
    float g[8];
#pragma unroll
    for (int e = 0; e < 8; e++) { g[e] = ex[e] * inv; gates[(size_t)t * 8 + e] = g[e]; }
    int i0 = 0;
    for (int e = 1; e < 8; e++) if (g[e] > g[i0]) i0 = e;
    int i1 = (i0 == 0) ? 1 : 0;
    for (int e = 0; e < 8; e++) if (e != i0 && g[e] > g[i1]) i1 = e;
    vals[t] = make_float2(g[i0], g[i1]);
    eidx[t] = make_int2(i0, i1);
  }
}

// ---------------- scan: 8-wave parallel chunked ballot cumsum ----------------
__global__ __launch_bounds__(512) void k_scan(
    const int2* __restrict__ eidx, const float* __restrict__ gates,
    int* __restrict__ ppad, float* __restrict__ out_tail) {
  __shared__ short se0[T_TOK], se1[T_TOK];
  __shared__ int cc[2][64][8];   // per-j, per-chunk(64 tok), per-expert counts
  __shared__ int cb[2][64][8];   // exclusive prefix bases
  __shared__ float gsum[8][8];
  __shared__ int ctot[8], c0tot[8];
  const int tid = threadIdx.x, lane = tid & 63, wid = tid >> 6;
  for (int i = tid; i < T_TOK; i += 512) {
    int2 e2 = eidx[i];
    se0[i] = (short)e2.x; se1[i] = (short)e2.y;
  }
  __syncthreads();
  // phase 1: per-chunk counts
  for (int c = wid * 8; c < wid * 8 + 8; ++c) {
    const int t = c * 64 + lane;
    const int e0 = se0[t], e1 = se1[t];
#pragma unroll
    for (int e = 0; e < 8; ++e) {
      unsigned long long m0 = __ballot(e0 == e);
      unsigned long long m1 = __ballot(e1 == e);
      if (lane == e) { cc[0][c][e] = __popcll(m0); cc[1][c][e] = __popcll(m1); }
    }
  }
  __syncthreads();
  // phase 2: per-expert exclusive prefix over (j=0 chunks, then j=1 chunks)
  {
    const int e = wid;  // wave e handles expert e
    int v0 = cc[0][lane][e], v1 = cc[1][lane][e];
    int p0 = v0, p1 = v1;
#pragma unroll
    for (int o = 1; o < 64; o <<= 1) {
      int u0 = __shfl_up(p0, o), u1 = __shfl_up(p1, o);
      if (lane >= o) { p0 += u0; p1 += u1; }
    }
    const int tot0 = __shfl(p0, 63), tot1 = __shfl(p1, 63);
    cb[0][lane][e] = p0 - v0;
    cb[1][lane][e] = p1 - v1 + tot0;  // slot-1 positions come after all slot-0 counts
    if (lane == 0) { c0tot[e] = tot0; ctot[e] = tot0 + tot1; }
  }
  __syncthreads();
  // phase 3: per-token positions
  for (int c = wid * 8; c < wid * 8 + 8; ++c) {
    const int t = c * 64 + lane;
    const unsigned long long lt = (lane == 63) ? 0x7fffffffffffffffull
                                               : ((1ull << lane) - 1ull);
    const int e0 = se0[t], e1 = se1[t];
    int p0 = 0, p1 = 0;
#pragma unroll
    for (int e = 0; e < 8; ++e) {
      unsigned long long m0 = __ballot(e0 == e);
      unsigned long long m1 = __ballot(e1 == e);
      if (e0 == e) p0 = cb[0][c][e] + __popcll(m0 & lt);
      if (e1 == e) p1 = cb[1][c][e] + __popcll(m1 & lt);
    }
    ppad[2 * t]     = (p0 < CAPN) ? p0 : CAPN;
    ppad[2 * t + 1] = (p1 < CAPN) ? p1 : CAPN;
  }
  // phase 4: gate sums for l_aux
  float acc[8];
#pragma unroll
  for (int e = 0; e < 8; ++e) acc[e] = 0.f;
  for (int t = tid; t < T_TOK; t += 512) {
    const float4 a = ((const float4*)(gates + (size_t)t * 8))[0];
    const float4 b = ((const float4*)(gates + (size_t)t * 8))[1];
    acc[0] += a.x; acc[1] += a.y; acc[2] += a.z; acc[3] += a.w;
    acc[4] += b.x; acc[5] += b.y; acc[6] += b.z; acc[7] += b.w;
  }
#pragma unroll
  for (int e = 0; e < 8; ++e)
#pragma unroll
    for (int o = 32; o > 0; o >>= 1) acc[e] += __shfl_down(acc[e], o);
  if (lane == 0) {
#pragma unroll
    for (int e = 0; e < 8; ++e) gsum[wid][e] = acc[e];
  }
  __syncthreads();
  if (tid == 0) {
    float la = 0.f;
#pragma unroll
    for (int e = 0; e < 8; ++e) {
      float sg = 0.f;
#pragma unroll
      for (int w = 0; w < 8; ++w) sg += gsum[w][e];
      la += (sg * (1.0f / T_TOK)) * ((float)c0tot[e] * (1.0f / T_TOK));
    }
    out_tail[0] = la * 8.0f;
#pragma unroll
    for (int e = 0; e < 8; ++e) out_tail[1 + e] = (float)ctot[e];
  }
}

// ---------------- scatter kept tokens into expert buffer ----------------
__global__ __launch_bounds__(128) void k_scatter(
    const unsigned short* __restrict__ xn, const int2* __restrict__ eidx,
    const int* __restrict__ ppad, unsigned short* __restrict__ buf) {
  const int b = blockIdx.x;
  const int t = b >> 1, j = b & 1;
  const int pp = ppad[2 * t + j];
  if (pp >= CAPN) return;
  const int2 e2 = eidx[t];
  const int e = j ? e2.y : e2.x;
  const uint4* s = (const uint4*)(xn + (size_t)t * HD);
  uint4* d = (uint4*)(buf + ((size_t)e * CAPN + pp) * HD);
  d[threadIdx.x] = s[threadIdx.x];
}

// ---------------- fp32->bf16 convert + transpose ----------------
// in: [E][R][C] f32 ; out: [E][C][R] bf16.  grid (C/64, R/64, E), 256 thr.
__global__ __launch_bounds__(256) void k_convT(
    const float* __restrict__ Win, unsigned short* __restrict__ Wout,
    int R, int C) {
  __shared__ __align__(16) unsigned short tile[64][72];
  const int e = blockIdx.z;
  const int c0 = blockIdx.x * 64, r0 = blockIdx.y * 64;
  const int tid = threadIdx.x;
  const int r = tid >> 2, qq = tid & 3;
  const float* src = Win + ((size_t)e * R + r0 + r) * C + c0;
#pragma unroll
  for (int i = 0; i < 4; i++) {
    const int cc = qq * 16 + i * 4;
    const float4 v = *(const float4*)(src + cc);
    tile[cc + 0][r] = f2b(v.x);
    tile[cc + 1][r] = f2b(v.y);
    tile[cc + 2][r] = f2b(v.z);
    tile[cc + 3][r] = f2b(v.w);
  }
  __syncthreads();
  // store: 8 lanes per output row -> 128B contiguous segments per wave
  const int cr = tid >> 3, q8 = tid & 7;
  unsigned short* dst0 = Wout + ((size_t)e * C + c0 + cr) * R + r0 + q8 * 8;
  *(uint4*)dst0 = *(const uint4*)&tile[cr][q8 * 8];
  unsigned short* dst1 = Wout + ((size_t)e * C + c0 + cr + 32) * R + r0 + q8 * 8;
  *(uint4*)dst1 = *(const uint4*)&tile[cr + 32][q8 * 8];
}

// ---------------- 256x256 8-phase GEMM (m201 template) ----------------
// MODE 0: h1 = gelu(buf @ W1T^T + b1) -> bf16 ; SPLITK=1
// MODE 1: y  = h1 @ W2T^T (no bias)   -> f32 partial per z ; SPLITK=2
#define GLL(SRCP, DOFF) __builtin_amdgcn_global_load_lds( \
    (const __attribute__((address_space(1))) void*)(SRCP), \
    (__attribute__((address_space(3))) void*)(smem + (DOFF)), 16, 0, 0)

#define ST_A(S, KO) { \
  GLL(gA + (size_t)(KO) + stOff,             (S)*65536 + wid*1024); \
  GLL(gA + (size_t)(KO) + stOff + 64*LDK,    (S)*65536 + 8192 + wid*1024); \
  GLL(gA + (size_t)(KO) + stOff + 128*LDK,   (S)*65536 + 16384 + wid*1024); \
  GLL(gA + (size_t)(KO) + stOff + 192*LDK,   (S)*65536 + 24576 + wid*1024); }

#define ST_B(S, KO) { \
  GLL(gB + (size_t)(KO) + stOff,             (S)*65536 + 32768 + wid*1024); \
  GLL(gB + (size_t)(KO) + stOff + 64*LDK,    (S)*65536 + 40960 + wid*1024); \
  GLL(gB + (size_t)(KO) + stOff + 128*LDK,   (S)*65536 + 49152 + wid*1024); \
  GLL(gB + (size_t)(KO) + stOff + 192*LDK,   (S)*65536 + 57344 + wid*1024); }

#define RD_A(S, MH) { _Pragma("unroll") for (int f = 0; f < 4; ++f) { \
    aR[f*2+0] = *(const short8*)(smem + (S)*65536 + wrBase + ((MH)*4+f)*2048 + loff0); \
    aR[f*2+1] = *(const short8*)(smem + (S)*65536 + wrBase + ((MH)*4+f)*2048 + loff1); } }

#define RD_B(S, NH) { _Pragma("unroll") for (int g = 0; g < 2; ++g) { \
    bR[NH][g*2+0] = *(const short8*)(smem + (S)*65536 + 32768 + bBase + ((NH)*2+g)*2048 + loff0); \
    bR[NH][g*2+1] = *(const short8*)(smem + (S)*65536 + 32768 + bBase + ((NH)*2+g)*2048 + loff1); } }

#define MM(MH, NH) { __builtin_amdgcn_s_setprio(1); \
  _Pragma("unroll") for (int f = 0; f < 4; ++f) \
  _Pragma("unroll") for (int g = 0; g < 2; ++g) { \
    acc[(MH)*4+f][(NH)*2+g] = __builtin_amdgcn_mfma_f32_16x16x32_bf16(aR[f*2+0], bR[NH][g*2+0], acc[(MH)*4+f][(NH)*2+g], 0, 0, 0); \
    acc[(MH)*4+f][(NH)*2+g] = __builtin_amdgcn_mfma_f32_16x16x32_bf16(aR[f*2+1], bR[NH][g*2+1], acc[(MH)*4+f][(NH)*2+g], 0, 0, 0); } \
  __builtin_amdgcn_s_setprio(0); }

#define BARR __builtin_amdgcn_s_barrier()
#define LG0 asm volatile("s_waitcnt lgkmcnt(0)" ::: "memory")
#define VM8 asm volatile("s_waitcnt vmcnt(8)" ::: "memory")
#define VM0 asm volatile("s_waitcnt vmcnt(0)" ::: "memory")

// One iteration = 2 K-tiles (slot0 then slot1), 8 phases.
// Stage placement: B' after its last reader phase (ph2/ph6), A' after ph3/ph7.
#define ITER8(DOST, VM4TXT, VM8TXT, KK2, KK3) { \
  RD_A(0, 0); RD_B(0, 0); BARR; LG0; MM(0, 0); BARR; \
  RD_B(0, 1);             BARR; LG0; MM(0, 1); BARR; \
  RD_A(0, 1); if (DOST) { ST_B(0, KK2); } BARR; LG0; MM(1, 1); BARR; \
  if (DOST) { ST_A(0, KK2); } BARR; MM(1, 0); VM4TXT; BARR; \
  RD_A(1, 0); RD_B(1, 0); BARR; LG0; MM(0, 0); BARR; \
  RD_B(1, 1);             BARR; LG0; MM(0, 1); BARR; \
  RD_A(1, 1); if (DOST) { ST_B(1, KK3); } BARR; LG0; MM(1, 1); BARR; \
  if (DOST) { ST_A(1, KK3); } BARR; MM(1, 0); VM8TXT; BARR; }

template <int MODE, int SPLITK>
__global__ __launch_bounds__(512, 1) void k_gemm8p(
    const unsigned short* __restrict__ A, const unsigned short* __restrict__ Bt,
    const float* __restrict__ bias, void* __restrict__ out) {
  constexpr int LDK = MODE ? FD : HD;   // row stride (full K)
  constexpr int N = MODE ? HD : FD;
  constexpr int KLOC = LDK / SPLITK;
  constexpr int NI = KLOC / 128;        // iterations (2 K-tiles each)
  constexpr int NBT = N / 256;

  __shared__ __align__(16) unsigned char smem[131072];  // 2 slots x (A 32K + B 32K)

  const int tid = threadIdx.x;
  const int lane = tid & 63, wid = tid >> 6;
  const int l15 = lane & 15, lq = (lane >> 4) & 3;
  const int wr = wid >> 2, wc = wid & 3;

  // XCD-swizzled block mapping; lin = ((z*NBT + nt)<<5) | mt
  const int nwg = gridDim.x;
  const int per = nwg >> 3;
  const int lin = blockIdx.x;
  const int swz = (lin & 7) * per + (lin >> 3);
  const int mt = swz & 31;
  const int rest = swz >> 5;
  const int nt = rest % NBT;
  const int z = rest / NBT;

  const int e = mt >> 2;
  const size_t m0 = (size_t)mt * 256;
  const int n0 = nt * 256;
  const unsigned short* gA = A + m0 * (size_t)LDK + (size_t)z * KLOC;
  const unsigned short* gB = Bt + ((size_t)e * N + n0) * (size_t)LDK + (size_t)z * KLOC;

  // staging: thread tid covers LDS-linear chunk tid (row tid>>3, phys chunk tid&7)
  // source chunk = phys ^ (row&7)  (involution with read-side swizzle)
  const int stOff = (tid >> 3) * LDK + (((tid & 7) ^ ((tid >> 3) & 7)) << 3);

  // fragment read offsets (bytes): row l15, logical chunk ks*4+lq, XOR row&7
  const int loff0 = l15 * 128 + (((0 + lq) ^ (l15 & 7)) << 4);
  const int loff1 = l15 * 128 + (((4 + lq) ^ (l15 & 7)) << 4);
  const int wrBase = wr * 16384;
  const int bBase = (wc >> 1) * 16384 + (wc & 1) * 8192;

  short8 aR[8];
  short8 bR[2][8];
  f32x4 acc[8][4];
  const f32x4 fz = {0.f, 0.f, 0.f, 0.f};
#pragma unroll
  for (int mi = 0; mi < 8; mi++)
#pragma unroll
    for (int ni = 0; ni < 4; ni++) acc[mi][ni] = fz;

  // prologue: stage tile0 -> slot0, tile1 -> slot1; wait tile0 landed
  ST_A(0, 0); ST_B(0, 0);
  ST_A(1, 64); ST_B(1, 64);
  VM8; BARR;

  int kk = 0;
  for (int it = 0; it < NI - 1; ++it, kk += 128) {
    ITER8(true, VM8, VM8, kk + 128, kk + 192);
  }
  ITER8(false, VM0, , 0, 0);

  const int colB = n0 + wc * 64 + l15;
  const size_t rowB = m0 + (size_t)wr * 128 + lq * 4;
  if (MODE == 0) {
    unsigned short* o = (unsigned short*)out;
    const float* brow = bias + (size_t)e * N;
#pragma unroll
    for (int mi = 0; mi < 8; ++mi)
#pragma unroll
      for (int ni = 0; ni < 4; ++ni) {
        const int col = colB + ni * 16;
        const float bv = brow[col];
#pragma unroll
        for (int r = 0; r < 4; ++r) {
          const size_t row = rowB + mi * 16 + r;
          const float pre = acc[mi][ni][r] + bv;
          const float g = 0.5f * pre * (1.0f + erff(pre * 0.70710678118654752f));
          o[row * (size_t)N + col] = f2b(g);
        }
      }
  } else {
    float* yp = (float*)out + (size_t)z * (8192ull * 1024ull);
#pragma unroll
    for (int mi = 0; mi < 8; ++mi)
#pragma unroll
      for (int ni = 0; ni < 4; ++ni) {
        const int col = colB + ni * 16;
#pragma unroll
        for (int r = 0; r < 4; ++r) {
          const size_t row = rowB + mi * 16 + r;
          yp[row * (size_t)N + col] = acc[mi][ni][r];
        }
      }
  }
}
#undef ITER8
#undef VM0
#undef VM8
#undef LG0
#undef BARR
#undef MM
#undef RD_B
#undef RD_A
#undef ST_B
#undef ST_A
#undef GLL

// ---------------- combine: out = x + sum_j w_j * (y[slot_j] + b2[e_j]) ------
template <int SPLIT>
__global__ __launch_bounds__(256) void k_combine(
    const float* __restrict__ x, const float* __restrict__ y0,
    const float* __restrict__ y1, const float* __restrict__ b2,
    const int2* __restrict__ eidx, const int* __restrict__ ppad,
    const float2* __restrict__ vals, float* __restrict__ out) {
  const int t = blockIdx.x, tid = threadIdx.x;
  const float2 v = vals[t];
  const int2 e2 = eidx[t];
  const int p0 = ppad[2 * t], p1 = ppad[2 * t + 1];
  const float k0 = (p0 < CAPN) ? v.x : 0.f;
  const float k1 = (p1 < CAPN) ? v.y : 0.f;
  const float inv = 1.0f / (k0 + k1 + 1e-9f);
  const float w0 = k0 * inv, w1 = k1 * inv;
  float4 o = ((const float4*)(x + (size_t)t * HD))[tid];
  if (p0 < CAPN) {
    const size_t s = ((size_t)e2.x * CAPN + p0) * HD;
    float4 a = ((const float4*)(y0 + s))[tid];
    if (SPLIT == 2) {
      const float4 b = ((const float4*)(y1 + s))[tid];
      a.x += b.x; a.y += b.y; a.z += b.z; a.w += b.w;
    }
    const float4 bb = ((const float4*)(b2 + (size_t)e2.x * HD))[tid];
    o.x += w0 * (a.x + bb.x); o.y += w0 * (a.y + bb.y);
    o.z += w0 * (a.z + bb.z); o.w += w0 * (a.w + bb.w);
  }
  if (p1 < CAPN) {
    const size_t s = ((size_t)e2.y * CAPN + p1) * HD;
    float4 a = ((const float4*)(y0 + s))[tid];
    if (SPLIT == 2) {
      const float4 b = ((const float4*)(y1 + s))[tid];
      a.x += b.x; a.y += b.y; a.z += b.z; a.w += b.w;
    }
    const float4 bb = ((const float4*)(b2 + (size_t)e2.y * HD))[tid];
    o.x += w1 * (a.x + bb.x); o.y += w1 * (a.y + bb.y);
    o.z += w1 * (a.z + bb.z); o.w += w1 * (a.w + bb.w);
  }
  ((float4*)(out + (size_t)t * HD))[tid] = o;
}

extern "C" void kernel_launch(void* const* d_in, const int* in_sizes, int n_in,
                              void* d_out, int out_size, void* d_ws, size_t ws_size,
                              hipStream_t stream) {
  const float* x     = (const float*)d_in[0];
  const float* gamma = (const float*)d_in[1];
  const float* beta  = (const float*)d_in[2];
  const float* wg    = (const float*)d_in[3];
  const float* W1    = (const float*)d_in[4];
  const float* b1    = (const float*)d_in[5];
  const float* W2    = (const float*)d_in[6];
  const float* b2    = (const float*)d_in[7];
  float* out = (float*)d_out;

  char* ws = (char*)d_ws;
  // layout: smalls | xn 8M | buf 16M | h1 64M | WT 64M | y0 32M | y1 32M
  float* gates        = (float*)(ws);                                  // 128K
  float2* vals        = (float2*)(ws + (128ull << 10));                // 32K
  int2* eidx          = (int2*)(ws + (160ull << 10));                  // 32K
  int* ppad           = (int*)(ws + (192ull << 10));                   // 32K
  unsigned short* xn  = (unsigned short*)(ws + (512ull << 10));
  unsigned short* buf = (unsigned short*)(ws + (512ull << 10) + (8ull << 20));
  unsigned short* h1  = (unsigned short*)(ws + (512ull << 10) + (24ull << 20));
  unsigned short* WT  = (unsigned short*)(ws + (512ull << 10) + (88ull << 20));
  float* y0           = (float*)(ws + (512ull << 10) + (152ull << 20));
  float* y1           = (float*)(ws + (512ull << 10) + (184ull << 20));
  const bool splitk = ws_size >= ((217ull << 20));

  k_ln_gate<<<T_TOK, 256, 0, stream>>>(x, gamma, beta, wg, xn, gates, vals, eidx);
  k_scan<<<1, 512, 0, stream>>>(eidx, gates, ppad, out + (size_t)T_TOK * HD);
  k_scatter<<<T_TOK * 2, 128, 0, stream>>>(xn, eidx, ppad, buf);
  k_convT<<<dim3(FD / 64, HD / 64, NE), 256, 0, stream>>>(W1, WT, HD, FD);
  k_gemm8p<0, 1><<<512, 512, 0, stream>>>(buf, WT, b1, h1);
  k_convT<<<dim3(HD / 64, FD / 64, NE), 256, 0, stream>>>(W2, WT, FD, HD);
  if (splitk) {
    k_gemm8p<1, 2><<<256, 512, 0, stream>>>(h1, WT, nullptr, y0);
    k_combine<2><<<T_TOK, 256, 0, stream>>>(x, y0, y1, b2, eidx, ppad, vals, out);
  } else {
    k_gemm8p<1, 1><<<128, 512, 0, stream>>>(h1, WT, nullptr, y0);
    k_combine<1><<<T_TOK, 256, 0, stream>>>(x, y0, y1, b2, eidx, ppad, vals, out);
  }
}

// Round 4
// 517.317 us; speedup vs baseline: 1.2238x; 1.0263x over previous
//
#include <hip/hip_runtime.h>
#include <hip/hip_bf16.h>
#include <math.h>

// DeepSpeed MoE block on MI355X.
// ln_gate -> scan -> scatter -> convT(W1) -> gemm8p<0>(gelu) -> convT(W2) ->
// gemm8p<1>(split-K, bf16 partials) -> combine.
// GEMM: 256x256 8-phase, BK=64, 8 waves, 2-slot LDS dbuf, counted vmcnt,
// XOR-swizzled LDS, expert-per-XCD block mapping (mt quad = expert = XCD),
// LDS-transposed coalesced bf16 epilogue.

#define T_TOK 4096
#define HD 1024
#define NE 8
#define FD 4096
#define CAPN 1024

typedef __attribute__((ext_vector_type(8))) short short8;
typedef __attribute__((ext_vector_type(4))) float f32x4;

__device__ __forceinline__ unsigned short f2b(float f) {
  __hip_bfloat16 h = __float2bfloat16(f);
  unsigned short u;
  __builtin_memcpy(&u, &h, 2);
  return u;
}
__device__ __forceinline__ float b2f(unsigned short u) {
  unsigned v = ((unsigned)u) << 16;
  float f;
  __builtin_memcpy(&f, &v, 4);
  return f;
}

// ---------------- LayerNorm + gating (softmax + top-2) ----------------
__global__ __launch_bounds__(256) void k_ln_gate(
    const float* __restrict__ x, const float* __restrict__ gamma,
    const float* __restrict__ beta, const float* __restrict__ wg,
    unsigned short* __restrict__ xn, float* __restrict__ gates,
    float2* __restrict__ vals, int2* __restrict__ eidx) {
  const int t = blockIdx.x;
  const int tid = threadIdx.x;
  const int lane = tid & 63, wid = tid >> 6;
  __shared__ float red[4];
  __shared__ float pr2[256][9];

  const float4 v = ((const float4*)(x + (size_t)t * HD))[tid];
  float s = v.x + v.y + v.z + v.w;
#pragma unroll
  for (int o = 32; o > 0; o >>= 1) s += __shfl_down(s, o);
  if (lane == 0) red[wid] = s;
  __syncthreads();
  const float mean = (red[0] + red[1] + red[2] + red[3]) * (1.0f / HD);
  float dv[4];
  dv[0] = v.x - mean; dv[1] = v.y - mean; dv[2] = v.z - mean; dv[3] = v.w - mean;
  float q = dv[0]*dv[0] + dv[1]*dv[1] + dv[2]*dv[2] + dv[3]*dv[3];
  __syncthreads();
#pragma unroll
  for (int o = 32; o > 0; o >>= 1) q += __shfl_down(q, o);
  if (lane == 0) red[wid] = q;
  __syncthreads();
  const float var = (red[0] + red[1] + red[2] + red[3]) * (1.0f / HD);
  const float rs = 1.0f / sqrtf(var + 1e-5f);

  const float4 gm = ((const float4*)gamma)[tid];
  const float4 bt = ((const float4*)beta)[tid];
  float xv[4];
  xv[0] = dv[0] * rs * gm.x + bt.x;
  xv[1] = dv[1] * rs * gm.y + bt.y;
  xv[2] = dv[2] * rs * gm.z + bt.z;
  xv[3] = dv[3] * rs * gm.w + bt.w;
  ushort4 o4;
  o4.x = f2b(xv[0]); o4.y = f2b(xv[1]); o4.z = f2b(xv[2]); o4.w = f2b(xv[3]);
  ((ushort4*)(xn + (size_t)t * HD))[tid] = o4;

  float p[8];
#pragma unroll
  for (int e = 0; e < 8; e++) p[e] = 0.f;
  const int c0 = tid * 4;
#pragma unroll
  for (int i = 0; i < 4; i++) {
    const float4 w0 = ((const float4*)(wg + (size_t)(c0 + i) * NE))[0];
    const float4 w1 = ((const float4*)(wg + (size_t)(c0 + i) * NE))[1];
    p[0] += xv[i] * w0.x; p[1] += xv[i] * w0.y;
    p[2] += xv[i] * w0.z; p[3] += xv[i] * w0.w;
    p[4] += xv[i] * w1.x; p[5] += xv[i] * w1.y;
    p[6] += xv[i] * w1.z; p[7] += xv[i] * w1.w;
  }
#pragma unroll
  for (int e = 0; e < 8; e++) pr2[tid][e] = p[e];
  __syncthreads();
  if (wid == 0) {
    const int e8 = lane & 7, g8 = lane >> 3;
    float s2 = 0.f;
#pragma unroll
    for (int i = 0; i < 32; ++i) s2 += pr2[g8 + 8 * i][e8];
    s2 += __shfl_xor(s2, 8);
    s2 += __shfl_xor(s2, 16);
    s2 += __shfl_xor(s2, 32);
    float lgv[8];
#pragma unroll
    for (int e = 0; e < 8; e++) lgv[e] = __shfl(s2, e);
    if (lane == 0) {
      float mx = lgv[0];
#pragma unroll
      for (int e = 1; e < 8; e++) mx = fmaxf(mx, lgv[e]);
      float ex[8], sum = 0.f;
#pragma unroll
      for (int e = 0; e < 8; e++) { ex[e] = expf(lgv[e] - mx); sum += ex[e]; }
      const float inv = 1.0f / sum;
      float g[8];
#pragma unroll
      for (int e = 0; e < 8; e++) { g[e] = ex[e] * inv; gates[(size_t)t * 8 + e] = g[e]; }
      int i0 = 0;
      for (int e = 1; e < 8; e++) if (g[e] > g[i0]) i0 = e;
      int i1 = (i0 == 0) ? 1 : 0;
      for (int e = 0; e < 8; e++) if (e != i0 && g[e] > g[i1]) i1 = e;
      vals[t] = make_float2(g[i0], g[i1]);
      eidx[t] = make_int2(i0, i1);
    }
  }
}

// ---------------- scan: 8-wave parallel chunked ballot cumsum ----------------
__global__ __launch_bounds__(512) void k_scan(
    const int2* __restrict__ eidx, const float* __restrict__ gates,
    int* __restrict__ ppad, float* __restrict__ out_tail) {
  __shared__ short se0[T_TOK], se1[T_TOK];
  __shared__ int cc[2][64][8];
  __shared__ int cb[2][64][8];
  __shared__ float gsum[8][8];
  __shared__ int ctot[8], c0tot[8];
  const int tid = threadIdx.x, lane = tid & 63, wid = tid >> 6;
  for (int i = tid; i < T_TOK; i += 512) {
    int2 e2 = eidx[i];
    se0[i] = (short)e2.x; se1[i] = (short)e2.y;
  }
  __syncthreads();
  for (int c = wid * 8; c < wid * 8 + 8; ++c) {
    const int t = c * 64 + lane;
    const int e0 = se0[t], e1 = se1[t];
#pragma unroll
    for (int e = 0; e < 8; ++e) {
      unsigned long long m0 = __ballot(e0 == e);
      unsigned long long m1 = __ballot(e1 == e);
      if (lane == e) { cc[0][c][e] = __popcll(m0); cc[1][c][e] = __popcll(m1); }
    }
  }
  __syncthreads();
  {
    const int e = wid;
    int v0 = cc[0][lane][e], v1 = cc[1][lane][e];
    int p0 = v0, p1 = v1;
#pragma unroll
    for (int o = 1; o < 64; o <<= 1) {
      int u0 = __shfl_up(p0, o), u1 = __shfl_up(p1, o);
      if (lane >= o) { p0 += u0; p1 += u1; }
    }
    const int tot0 = __shfl(p0, 63), tot1 = __shfl(p1, 63);
    cb[0][lane][e] = p0 - v0;
    cb[1][lane][e] = p1 - v1 + tot0;
    if (lane == 0) { c0tot[e] = tot0; ctot[e] = tot0 + tot1; }
  }
  __syncthreads();
  for (int c = wid * 8; c < wid * 8 + 8; ++c) {
    const int t = c * 64 + lane;
    const unsigned long long lt = (lane == 63) ? 0x7fffffffffffffffull
                                               : ((1ull << lane) - 1ull);
    const int e0 = se0[t], e1 = se1[t];
    int p0 = 0, p1 = 0;
#pragma unroll
    for (int e = 0; e < 8; ++e) {
      unsigned long long m0 = __ballot(e0 == e);
      unsigned long long m1 = __ballot(e1 == e);
      if (e0 == e) p0 = cb[0][c][e] + __popcll(m0 & lt);
      if (e1 == e) p1 = cb[1][c][e] + __popcll(m1 & lt);
    }
    ppad[2 * t]     = (p0 < CAPN) ? p0 : CAPN;
    ppad[2 * t + 1] = (p1 < CAPN) ? p1 : CAPN;
  }
  float acc[8];
#pragma unroll
  for (int e = 0; e < 8; ++e) acc[e] = 0.f;
  for (int t = tid; t < T_TOK; t += 512) {
    const float4 a = ((const float4*)(gates + (size_t)t * 8))[0];
    const float4 b = ((const float4*)(gates + (size_t)t * 8))[1];
    acc[0] += a.x; acc[1] += a.y; acc[2] += a.z; acc[3] += a.w;
    acc[4] += b.x; acc[5] += b.y; acc[6] += b.z; acc[7] += b.w;
  }
#pragma unroll
  for (int e = 0; e < 8; ++e)
#pragma unroll
    for (int o = 32; o > 0; o >>= 1) acc[e] += __shfl_down(acc[e], o);
  if (lane == 0) {
#pragma unroll
    for (int e = 0; e < 8; ++e) gsum[wid][e] = acc[e];
  }
  __syncthreads();
  if (tid == 0) {
    float la = 0.f;
#pragma unroll
    for (int e = 0; e < 8; ++e) {
      float sg = 0.f;
#pragma unroll
      for (int w = 0; w < 8; ++w) sg += gsum[w][e];
      la += (sg * (1.0f / T_TOK)) * ((float)c0tot[e] * (1.0f / T_TOK));
    }
    out_tail[0] = la * 8.0f;
#pragma unroll
    for (int e = 0; e < 8; ++e) out_tail[1 + e] = (float)ctot[e];
  }
}

// ---------------- scatter: one block per token, both slots ----------------
__global__ __launch_bounds__(128) void k_scatter(
    const unsigned short* __restrict__ xn, const int2* __restrict__ eidx,
    const int* __restrict__ ppad, unsigned short* __restrict__ buf) {
  const int t = blockIdx.x;
  const int2 e2 = eidx[t];
  const int p0 = ppad[2 * t], p1 = ppad[2 * t + 1];
  const uint4 v = ((const uint4*)(xn + (size_t)t * HD))[threadIdx.x];
  if (p0 < CAPN) ((uint4*)(buf + ((size_t)e2.x * CAPN + p0) * HD))[threadIdx.x] = v;
  if (p1 < CAPN) ((uint4*)(buf + ((size_t)e2.y * CAPN + p1) * HD))[threadIdx.x] = v;
}

// ---------------- fp32->bf16 convert + transpose ----------------
__global__ __launch_bounds__(256) void k_convT(
    const float* __restrict__ Win, unsigned short* __restrict__ Wout,
    int R, int C) {
  __shared__ __align__(16) unsigned short tile[64][72];
  const int e = blockIdx.z;
  const int c0 = blockIdx.x * 64, r0 = blockIdx.y * 64;
  const int tid = threadIdx.x;
  const int r = tid >> 2, qq = tid & 3;
  const float* src = Win + ((size_t)e * R + r0 + r) * C + c0;
#pragma unroll
  for (int i = 0; i < 4; i++) {
    const int cc = qq * 16 + i * 4;
    const float4 v = *(const float4*)(src + cc);
    tile[cc + 0][r] = f2b(v.x);
    tile[cc + 1][r] = f2b(v.y);
    tile[cc + 2][r] = f2b(v.z);
    tile[cc + 3][r] = f2b(v.w);
  }
  __syncthreads();
  const int cr = tid >> 3, q8 = tid & 7;
  unsigned short* dst0 = Wout + ((size_t)e * C + c0 + cr) * R + r0 + q8 * 8;
  *(uint4*)dst0 = *(const uint4*)&tile[cr][q8 * 8];
  unsigned short* dst1 = Wout + ((size_t)e * C + c0 + cr + 32) * R + r0 + q8 * 8;
  *(uint4*)dst1 = *(const uint4*)&tile[cr + 32][q8 * 8];
}

// ---------------- 256x256 8-phase GEMM, expert-per-XCD ----------------
// MODE 0: h1 = gelu(buf @ W1T^T + b1) -> bf16 ; SPLITK=1
// MODE 1: y  = h1 @ W2T^T (no bias)   -> bf16 partial per z ; SPLITK=2
#define GLL(SRCP, DOFF) __builtin_amdgcn_global_load_lds( \
    (const __attribute__((address_space(1))) void*)(SRCP), \
    (__attribute__((address_space(3))) void*)(smem + (DOFF)), 16, 0, 0)

#define ST_A(S, KO) { \
  GLL(gA + (size_t)(KO) + stOff,             (S)*65536 + wid*1024); \
  GLL(gA + (size_t)(KO) + stOff + 64*LDK,    (S)*65536 + 8192 + wid*1024); \
  GLL(gA + (size_t)(KO) + stOff + 128*LDK,   (S)*65536 + 16384 + wid*1024); \
  GLL(gA + (size_t)(KO) + stOff + 192*LDK,   (S)*65536 + 24576 + wid*1024); }

#define ST_B(S, KO) { \
  GLL(gB + (size_t)(KO) + stOff,             (S)*65536 + 32768 + wid*1024); \
  GLL(gB + (size_t)(KO) + stOff + 64*LDK,    (S)*65536 + 40960 + wid*1024); \
  GLL(gB + (size_t)(KO) + stOff + 128*LDK,   (S)*65536 + 49152 + wid*1024); \
  GLL(gB + (size_t)(KO) + stOff + 192*LDK,   (S)*65536 + 57344 + wid*1024); }

#define RD_A(S, MH) { _Pragma("unroll") for (int f = 0; f < 4; ++f) { \
    aR[f*2+0] = *(const short8*)(smem + (S)*65536 + wrBase + ((MH)*4+f)*2048 + loff0); \
    aR[f*2+1] = *(const short8*)(smem + (S)*65536 + wrBase + ((MH)*4+f)*2048 + loff1); } }

#define RD_B(S, NH) { _Pragma("unroll") for (int g = 0; g < 2; ++g) { \
    bR[NH][g*2+0] = *(const short8*)(smem + (S)*65536 + 32768 + bBase + ((NH)*2+g)*2048 + loff0); \
    bR[NH][g*2+1] = *(const short8*)(smem + (S)*65536 + 32768 + bBase + ((NH)*2+g)*2048 + loff1); } }

#define MM(MH, NH) { __builtin_amdgcn_s_setprio(1); \
  _Pragma("unroll") for (int f = 0; f < 4; ++f) \
  _Pragma("unroll") for (int g = 0; g < 2; ++g) { \
    acc[(MH)*4+f][(NH)*2+g] = __builtin_amdgcn_mfma_f32_16x16x32_bf16(aR[f*2+0], bR[NH][g*2+0], acc[(MH)*4+f][(NH)*2+g], 0, 0, 0); \
    acc[(MH)*4+f][(NH)*2+g] = __builtin_amdgcn_mfma_f32_16x16x32_bf16(aR[f*2+1], bR[NH][g*2+1], acc[(MH)*4+f][(NH)*2+g], 0, 0, 0); } \
  __builtin_amdgcn_s_setprio(0); }

#define BARR __builtin_amdgcn_s_barrier()
#define LG0 asm volatile("s_waitcnt lgkmcnt(0)" ::: "memory")
#define VM8 asm volatile("s_waitcnt vmcnt(8)" ::: "memory")
#define VM0 asm volatile("s_waitcnt vmcnt(0)" ::: "memory")

#define ITER8(DOST, VM4TXT, VM8TXT, KK2, KK3) { \
  RD_A(0, 0); RD_B(0, 0); BARR; LG0; MM(0, 0); BARR; \
  RD_B(0, 1);             BARR; LG0; MM(0, 1); BARR; \
  RD_A(0, 1); if (DOST) { ST_B(0, KK2); } BARR; LG0; MM(1, 1); BARR; \
  if (DOST) { ST_A(0, KK2); } BARR; MM(1, 0); VM4TXT; BARR; \
  RD_A(1, 0); RD_B(1, 0); BARR; LG0; MM(0, 0); BARR; \
  RD_B(1, 1);             BARR; LG0; MM(0, 1); BARR; \
  RD_A(1, 1); if (DOST) { ST_B(1, KK3); } BARR; LG0; MM(1, 1); BARR; \
  if (DOST) { ST_A(1, KK3); } BARR; MM(1, 0); VM8TXT; BARR; }

template <int MODE, int SPLITK>
__global__ __launch_bounds__(512, 1) void k_gemm8p(
    const unsigned short* __restrict__ A, const unsigned short* __restrict__ Bt,
    const float* __restrict__ bias, unsigned short* __restrict__ out) {
  constexpr int LDK = MODE ? FD : HD;
  constexpr int N = MODE ? HD : FD;
  constexpr int KLOC = LDK / SPLITK;
  constexpr int NI = KLOC / 128;
  constexpr int NBT = N / 256;

  __shared__ __align__(16) unsigned char smem[131072];

  const int tid = threadIdx.x;
  const int lane = tid & 63, wid = tid >> 6;
  const int l15 = lane & 15, lq = (lane >> 4) & 3;
  const int wr = wid >> 2, wc = wid & 3;

  // expert-per-XCD mapping: HW assigns block b -> XCD b%8.
  // xcd owns mt quad [4*xcd, 4*xcd+4) == expert xcd; nt (and z) iterate within.
  const int lin = blockIdx.x;
  const int xcd = lin & 7;
  const int i = lin >> 3;
  const int mt = (xcd << 2) | (i & 3);
  const int rest = i >> 2;
  const int nt = rest % NBT;
  const int z = rest / NBT;

  const int e = mt >> 2;
  const size_t m0 = (size_t)mt * 256;
  const int n0 = nt * 256;
  const unsigned short* gA = A + m0 * (size_t)LDK + (size_t)z * KLOC;
  const unsigned short* gB = Bt + ((size_t)e * N + n0) * (size_t)LDK + (size_t)z * KLOC;

  const int stOff = (tid >> 3) * LDK + (((tid & 7) ^ ((tid >> 3) & 7)) << 3);
  const int loff0 = l15 * 128 + (((0 + lq) ^ (l15 & 7)) << 4);
  const int loff1 = l15 * 128 + (((4 + lq) ^ (l15 & 7)) << 4);
  const int wrBase = wr * 16384;
  const int bBase = (wc >> 1) * 16384 + (wc & 1) * 8192;

  short8 aR[8];
  short8 bR[2][8];
  f32x4 acc[8][4];
  const f32x4 fz = {0.f, 0.f, 0.f, 0.f};
#pragma unroll
  for (int mi = 0; mi < 8; mi++)
#pragma unroll
    for (int ni = 0; ni < 4; ni++) acc[mi][ni] = fz;

  ST_A(0, 0); ST_B(0, 0);
  ST_A(1, 64); ST_B(1, 64);
  VM8; BARR;

  int kk = 0;
  for (int it = 0; it < NI - 1; ++it, kk += 128) {
    ITER8(true, VM8, VM8, kk + 128, kk + 192);
  }
  ITER8(false, VM0, , 0, 0);

  // ---- epilogue: per-wave LDS transpose -> coalesced bf16 stores ----
  unsigned short* o = out + (MODE ? (size_t)z * (8192ull * 1024ull) : 0);
  float bv[4];
  if (MODE == 0) {
    const float* brow = bias + (size_t)e * N;
#pragma unroll
    for (int ni = 0; ni < 4; ++ni) bv[ni] = brow[n0 + wc * 64 + ni * 16 + l15];
  }
  unsigned char* wbuf = smem + wid * 8192;
#pragma unroll
  for (int pass = 0; pass < 2; ++pass) {
#pragma unroll
    for (int mi4 = 0; mi4 < 4; ++mi4) {
#pragma unroll
      for (int ni = 0; ni < 4; ++ni) {
        const int cslot = ((ni ^ lq) << 4) + l15;  // XOR: bank-conflict-free
#pragma unroll
        for (int r = 0; r < 4; ++r) {
          const int lr = mi4 * 16 + lq * 4 + r;
          float vv = acc[pass * 4 + mi4][ni][r];
          if (MODE == 0) {
            vv += bv[ni];
            vv = 0.5f * vv * (1.0f + erff(vv * 0.70710678118654752f));
          }
          *(unsigned short*)(wbuf + lr * 128 + cslot * 2) = f2b(vv);
        }
      }
    }
    asm volatile("s_waitcnt lgkmcnt(0)" ::: "memory");
#pragma unroll
    for (int ii = 0; ii < 8; ++ii) {
      const int lr = ii * 8 + (lane >> 3);
      const uint4 d = *(const uint4*)(wbuf + lr * 128 + (lane & 7) * 16);
      const int lqr = (lr >> 2) & 3;
      const int colo = ((((lane >> 1) & 3) ^ lqr) << 4) + (lane & 1) * 8;
      const size_t row = m0 + (size_t)wr * 128 + pass * 64 + lr;
      *(uint4*)(o + row * (size_t)N + n0 + wc * 64 + colo) = d;
    }
    asm volatile("s_waitcnt lgkmcnt(0)" ::: "memory");
  }
}
#undef ITER8
#undef VM0
#undef VM8
#undef LG0
#undef BARR
#undef MM
#undef RD_B
#undef RD_A
#undef ST_B
#undef ST_A
#undef GLL

// ---------------- combine: out = x + sum_j w_j * (y[slot_j] + b2[e_j]) ------
template <int SPLIT>
__global__ __launch_bounds__(256) void k_combine(
    const float* __restrict__ x, const unsigned short* __restrict__ y0,
    const unsigned short* __restrict__ y1, const float* __restrict__ b2,
    const int2* __restrict__ eidx, const int* __restrict__ ppad,
    const float2* __restrict__ vals, float* __restrict__ out) {
  const int t = blockIdx.x, tid = threadIdx.x;
  const float2 v = vals[t];
  const int2 e2 = eidx[t];
  const int p0 = ppad[2 * t], p1 = ppad[2 * t + 1];
  const float k0 = (p0 < CAPN) ? v.x : 0.f;
  const float k1 = (p1 < CAPN) ? v.y : 0.f;
  const float inv = 1.0f / (k0 + k1 + 1e-9f);
  const float w0 = k0 * inv, w1 = k1 * inv;
  float4 o = ((const float4*)(x + (size_t)t * HD))[tid];
  if (p0 < CAPN) {
    const size_t s = ((size_t)e2.x * CAPN + p0) * HD;
    const ushort4 a = ((const ushort4*)(y0 + s))[tid];
    float ax = b2f(a.x), ay = b2f(a.y), az = b2f(a.z), aw = b2f(a.w);
    if (SPLIT == 2) {
      const ushort4 b = ((const ushort4*)(y1 + s))[tid];
      ax += b2f(b.x); ay += b2f(b.y); az += b2f(b.z); aw += b2f(b.w);
    }
    const float4 bb = ((const float4*)(b2 + (size_t)e2.x * HD))[tid];
    o.x += w0 * (ax + bb.x); o.y += w0 * (ay + bb.y);
    o.z += w0 * (az + bb.z); o.w += w0 * (aw + bb.w);
  }
  if (p1 < CAPN) {
    const size_t s = ((size_t)e2.y * CAPN + p1) * HD;
    const ushort4 a = ((const ushort4*)(y0 + s))[tid];
    float ax = b2f(a.x), ay = b2f(a.y), az = b2f(a.z), aw = b2f(a.w);
    if (SPLIT == 2) {
      const ushort4 b = ((const ushort4*)(y1 + s))[tid];
      ax += b2f(b.x); ay += b2f(b.y); az += b2f(b.z); aw += b2f(b.w);
    }
    const float4 bb = ((const float4*)(b2 + (size_t)e2.y * HD))[tid];
    o.x += w1 * (ax + bb.x); o.y += w1 * (ay + bb.y);
    o.z += w1 * (az + bb.z); o.w += w1 * (aw + bb.w);
  }
  ((float4*)(out + (size_t)t * HD))[tid] = o;
}

extern "C" void kernel_launch(void* const* d_in, const int* in_sizes, int n_in,
                              void* d_out, int out_size, void* d_ws, size_t ws_size,
                              hipStream_t stream) {
  const float* x     = (const float*)d_in[0];
  const float* gamma = (const float*)d_in[1];
  const float* beta  = (const float*)d_in[2];
  const float* wg    = (const float*)d_in[3];
  const float* W1    = (const float*)d_in[4];
  const float* b1    = (const float*)d_in[5];
  const float* W2    = (const float*)d_in[6];
  const float* b2    = (const float*)d_in[7];
  float* out = (float*)d_out;

  char* ws = (char*)d_ws;
  // layout: smalls 0.5M | xn 8M | buf 16M | h1 64M | WT 64M | y0 16M | y1 16M
  float* gates        = (float*)(ws);
  float2* vals        = (float2*)(ws + (128ull << 10));
  int2* eidx          = (int2*)(ws + (160ull << 10));
  int* ppad           = (int*)(ws + (192ull << 10));
  unsigned short* xn  = (unsigned short*)(ws + (512ull << 10));
  unsigned short* buf = (unsigned short*)(ws + (512ull << 10) + (8ull << 20));
  unsigned short* h1  = (unsigned short*)(ws + (512ull << 10) + (24ull << 20));
  unsigned short* WT  = (unsigned short*)(ws + (512ull << 10) + (88ull << 20));
  unsigned short* y0  = (unsigned short*)(ws + (512ull << 10) + (152ull << 20));
  unsigned short* y1  = (unsigned short*)(ws + (512ull << 10) + (168ull << 20));
  const bool splitk = ws_size >= (186ull << 20);

  k_ln_gate<<<T_TOK, 256, 0, stream>>>(x, gamma, beta, wg, xn, gates, vals, eidx);
  k_scan<<<1, 512, 0, stream>>>(eidx, gates, ppad, out + (size_t)T_TOK * HD);
  k_scatter<<<T_TOK, 128, 0, stream>>>(xn, eidx, ppad, buf);
  k_convT<<<dim3(FD / 64, HD / 64, NE), 256, 0, stream>>>(W1, WT, HD, FD);
  k_gemm8p<0, 1><<<512, 512, 0, stream>>>(buf, WT, b1, h1);
  k_convT<<<dim3(HD / 64, FD / 64, NE), 256, 0, stream>>>(W2, WT, FD, HD);
  if (splitk) {
    k_gemm8p<1, 2><<<256, 512, 0, stream>>>(h1, WT, nullptr, y0);
    k_combine<2><<<T_TOK, 256, 0, stream>>>(x, y0, y1, b2, eidx, ppad, vals, out);
  } else {
    k_gemm8p<1, 1><<<128, 512, 0, stream>>>(h1, WT, nullptr, y0);
    k_combine<1><<<T_TOK, 256, 0, stream>>>(x, y0, y1, b2, eidx, ppad, vals, out);
  }
}